// Round 3
// baseline (2111.224 us; speedup 1.0000x reference)
//
#include <hip/hip_runtime.h>
#include <math.h>

#define N_NODES 50000
#define N_EDGES 400000
#define D 128
#define TM 64   // rows (edges/nodes) per block

using f4 = float4;

// Stage a 64x128 fp32 weight chunk into LDS. 8192 floats = 2048 float4,
// 256 threads x 8 float4 each, fully coalesced.
__device__ __forceinline__ void stage_w(const float* __restrict__ W,
                                        float (*sW)[128], int t) {
    const f4* s4 = (const f4*)W;
    f4* d4 = (f4*)&sW[0][0];
#pragma unroll
    for (int i = 0; i < 8; ++i) d4[t + i * 256] = s4[t + i * 256];
}

// 64-step K inner product, 4 k-steps per iteration, float4 LDS loads on both
// sides (12 DS instrs per 128 FMAs). A from sA (row-major, SA_STRIDE floats),
// B from sW. Each thread: 4 rows x 8 cols.
template <int SA_STRIDE>
__device__ __forceinline__ void kloop(const float* __restrict__ sA, int a_col0,
                                      const float (*sW)[128],
                                      int r0, int c0, float acc[4][8]) {
#pragma unroll 2
    for (int k = 0; k < 64; k += 4) {
        f4 av[4];
#pragma unroll
        for (int i = 0; i < 4; ++i)
            av[i] = *(const f4*)&sA[(r0 + i) * SA_STRIDE + a_col0 + k];
        float bv[4][8];
#pragma unroll
        for (int kk = 0; kk < 4; ++kk) {
            const f4 b0 = *(const f4*)&sW[k + kk][c0];
            const f4 b1 = *(const f4*)&sW[k + kk][c0 + 4];
            bv[kk][0] = b0.x; bv[kk][1] = b0.y; bv[kk][2] = b0.z; bv[kk][3] = b0.w;
            bv[kk][4] = b1.x; bv[kk][5] = b1.y; bv[kk][6] = b1.z; bv[kk][7] = b1.w;
        }
#pragma unroll
        for (int kk = 0; kk < 4; ++kk) {
            const float a0 = ((const float*)&av[0])[kk];
            const float a1 = ((const float*)&av[1])[kk];
            const float a2 = ((const float*)&av[2])[kk];
            const float a3 = ((const float*)&av[3])[kk];
#pragma unroll
            for (int j = 0; j < 8; ++j) {
                acc[0][j] = fmaf(a0, bv[kk][j], acc[0][j]);
                acc[1][j] = fmaf(a1, bv[kk][j], acc[1][j]);
                acc[2][j] = fmaf(a2, bv[kk][j], acc[2][j]);
                acc[3][j] = fmaf(a3, bv[kk][j], acc[3][j]);
            }
        }
    }
}

__device__ __forceinline__ void zero_acc(float acc[4][8]) {
#pragma unroll
    for (int i = 0; i < 4; ++i)
#pragma unroll
        for (int j = 0; j < 8; ++j) acc[i][j] = 0.f;
}

__device__ __forceinline__ void bias_relu_to_sH(const float* __restrict__ b,
                                                float acc[4][8],
                                                float (*sH)[128],
                                                int r0, int c0) {
    const f4 bb0 = *(const f4*)&b[c0];
    const f4 bb1 = *(const f4*)&b[c0 + 4];
    const float bv[8] = {bb0.x, bb0.y, bb0.z, bb0.w,
                         bb1.x, bb1.y, bb1.z, bb1.w};
#pragma unroll
    for (int i = 0; i < 4; ++i) {
        f4 o0, o1;
        o0.x = fmaxf(acc[i][0] + bv[0], 0.f);
        o0.y = fmaxf(acc[i][1] + bv[1], 0.f);
        o0.z = fmaxf(acc[i][2] + bv[2], 0.f);
        o0.w = fmaxf(acc[i][3] + bv[3], 0.f);
        o1.x = fmaxf(acc[i][4] + bv[4], 0.f);
        o1.y = fmaxf(acc[i][5] + bv[5], 0.f);
        o1.z = fmaxf(acc[i][6] + bv[6], 0.f);
        o1.w = fmaxf(acc[i][7] + bv[7], 0.f);
        *(f4*)&sH[r0 + i][c0]     = o0;
        *(f4*)&sH[r0 + i][c0 + 4] = o1;
    }
}

// ---------------- edge kernel ----------------
// edge_in = [nf[snd], nf[rcv], ef]  (K=384) -> 128 relu -> 128 relu -> 128
// -> LN -> atomicAdd into agg[rcv] (staged in node-out region of d_out),
// write (LN + ef) to edge_out
__global__ __launch_bounds__(256, 2)
void edge_kernel(const float* __restrict__ nf, const float* __restrict__ ef,
                 const int* __restrict__ snd, const int* __restrict__ rcv,
                 const float* __restrict__ W1, const float* __restrict__ b1,
                 const float* __restrict__ W2, const float* __restrict__ b2,
                 const float* __restrict__ W3, const float* __restrict__ b3,
                 const float* __restrict__ gam, const float* __restrict__ bet,
                 float* __restrict__ edge_out, float* __restrict__ agg) {
    __shared__ float sX[TM][64];    // 16 KiB  (layer-1 A chunk, gathered)
    __shared__ float sW[64][128];   // 32 KiB  (weight chunk)
    __shared__ float sH[TM][128];   // 32 KiB  (hidden activations)

    const int t  = threadIdx.x;
    const int r0 = (t >> 4) * 4;    // thread's first row
    const int c0 = (t & 15) * 8;    // thread's first col
    const int e0 = blockIdx.x * TM;

    const int ms = t >> 2;          // staging row (4 threads per row)
    const int ko = (t & 3) * 16;    // staging col offset

    float acc[4][8];
    zero_acc(acc);

    // ---- layer 1: K=384 in 6 chunks of 64 ----
    for (int kc = 0; kc < 6; ++kc) {
        __syncthreads();            // prev kloop's sX/sW reads done
        stage_w(W1 + (size_t)kc * 64 * 128, sW, t);
        {
            const int e = e0 + ms;
            const float* src;
            if (kc < 2)      src = nf + (size_t)snd[e] * D + kc * 64;
            else if (kc < 4) src = nf + (size_t)rcv[e] * D + (kc - 2) * 64;
            else             src = ef + (size_t)e * D + (kc - 4) * 64;
            const f4* s4 = (const f4*)(src + ko);
            f4* d4 = (f4*)&sX[ms][ko];
#pragma unroll
            for (int i = 0; i < 4; ++i) d4[i] = s4[i];
        }
        __syncthreads();
        kloop<64>(&sX[0][0], 0, sW, r0, c0, acc);
    }
    bias_relu_to_sH(b1, acc, sH, r0, c0);

    // ---- layer 2: K=128, 2 chunks ----
    zero_acc(acc);
    for (int kc = 0; kc < 2; ++kc) {
        __syncthreads();            // sH writes visible / prev sW reads done
        stage_w(W2 + (size_t)kc * 64 * 128, sW, t);
        __syncthreads();
        kloop<128>(&sH[0][0], kc * 64, sW, r0, c0, acc);
    }
    __syncthreads();                // all sH reads done before overwrite
    bias_relu_to_sH(b2, acc, sH, r0, c0);

    // ---- layer 3: K=128, 2 chunks, linear ----
    zero_acc(acc);
    for (int kc = 0; kc < 2; ++kc) {
        __syncthreads();
        stage_w(W3 + (size_t)kc * 64 * 128, sW, t);
        __syncthreads();
        kloop<128>(&sH[0][0], kc * 64, sW, r0, c0, acc);
    }

    // ---- bias + LayerNorm + agg atomics + residual write ----
    {
        const f4 b30 = *(const f4*)&b3[c0];
        const f4 b31 = *(const f4*)&b3[c0 + 4];
        const float bv[8] = {b30.x, b30.y, b30.z, b30.w,
                             b31.x, b31.y, b31.z, b31.w};
        const f4 g0 = *(const f4*)&gam[c0];
        const f4 g1 = *(const f4*)&gam[c0 + 4];
        const float gv[8] = {g0.x, g0.y, g0.z, g0.w, g1.x, g1.y, g1.z, g1.w};
        const f4 be0 = *(const f4*)&bet[c0];
        const f4 be1 = *(const f4*)&bet[c0 + 4];
        const float ev[8] = {be0.x, be0.y, be0.z, be0.w,
                             be1.x, be1.y, be1.z, be1.w};

#pragma unroll
        for (int i = 0; i < 4; ++i) {
            float h[8];
            float s = 0.f, ss = 0.f;
#pragma unroll
            for (int j = 0; j < 8; ++j) {
                h[j] = acc[i][j] + bv[j];
                s += h[j];
                ss = fmaf(h[j], h[j], ss);
            }
            // reduce across the 16 lanes holding this row
#pragma unroll
            for (int m = 1; m < 16; m <<= 1) {
                s  += __shfl_xor(s, m, 64);
                ss += __shfl_xor(ss, m, 64);
            }
            const float mu   = s * (1.f / 128.f);
            const float var  = ss * (1.f / 128.f) - mu * mu;
            const float rstd = rsqrtf(var + 1e-6f);

            const int e = e0 + r0 + i;
            const int dst = rcv[e];
            float v[8];
#pragma unroll
            for (int j = 0; j < 8; ++j) {
                v[j] = (h[j] - mu) * rstd * gv[j] + ev[j];
                atomicAdd(&agg[(size_t)dst * D + c0 + j], v[j]);
            }
            const f4 er0 = *(const f4*)&ef[(size_t)e * D + c0];
            const f4 er1 = *(const f4*)&ef[(size_t)e * D + c0 + 4];
            f4 o0, o1;
            o0.x = v[0] + er0.x; o0.y = v[1] + er0.y;
            o0.z = v[2] + er0.z; o0.w = v[3] + er0.w;
            o1.x = v[4] + er1.x; o1.y = v[5] + er1.y;
            o1.z = v[6] + er1.z; o1.w = v[7] + er1.w;
            *(f4*)&edge_out[(size_t)e * D + c0]     = o0;
            *(f4*)&edge_out[(size_t)e * D + c0 + 4] = o1;
        }
    }
}

// ---------------- node kernel ----------------
// node_in = [nf, agg] (K=256) -> 128 relu -> 128 relu -> 128 -> LN
// -> write (LN + nf) to node_out. agg IS the node_out region (read fully
// before any write by the same block; no cross-block overlap).
__global__ __launch_bounds__(256, 2)
void node_kernel(const float* __restrict__ nf, const float* __restrict__ agg,
                 const float* __restrict__ W1, const float* __restrict__ b1,
                 const float* __restrict__ W2, const float* __restrict__ b2,
                 const float* __restrict__ W3, const float* __restrict__ b3,
                 const float* __restrict__ gam, const float* __restrict__ bet,
                 float* __restrict__ node_out) {
    __shared__ float sX[TM][64];
    __shared__ float sW[64][128];
    __shared__ float sH[TM][128];

    const int t  = threadIdx.x;
    const int r0 = (t >> 4) * 4;
    const int c0 = (t & 15) * 8;
    const int n0 = blockIdx.x * TM;

    const int ms = t >> 2;
    const int ko = (t & 3) * 16;

    float acc[4][8];
    zero_acc(acc);

    // ---- layer 1: K=256, 4 chunks of 64 ----
    for (int kc = 0; kc < 4; ++kc) {
        __syncthreads();
        stage_w(W1 + (size_t)kc * 64 * 128, sW, t);
        {
            int n = n0 + ms;
            if (n >= N_NODES) n = N_NODES - 1;   // clamp (last block only; row
                                                 // 49999 is owned by this block)
            const float* src = (kc < 2)
                ? nf  + (size_t)n * D + kc * 64
                : agg + (size_t)n * D + (kc - 2) * 64;
            const f4* s4 = (const f4*)(src + ko);
            f4* d4 = (f4*)&sX[ms][ko];
#pragma unroll
            for (int i = 0; i < 4; ++i) d4[i] = s4[i];
        }
        __syncthreads();
        kloop<64>(&sX[0][0], 0, sW, r0, c0, acc);
    }
    bias_relu_to_sH(b1, acc, sH, r0, c0);

    // ---- layer 2 ----
    zero_acc(acc);
    for (int kc = 0; kc < 2; ++kc) {
        __syncthreads();
        stage_w(W2 + (size_t)kc * 64 * 128, sW, t);
        __syncthreads();
        kloop<128>(&sH[0][0], kc * 64, sW, r0, c0, acc);
    }
    __syncthreads();
    bias_relu_to_sH(b2, acc, sH, r0, c0);

    // ---- layer 3 ----
    zero_acc(acc);
    for (int kc = 0; kc < 2; ++kc) {
        __syncthreads();
        stage_w(W3 + (size_t)kc * 64 * 128, sW, t);
        __syncthreads();
        kloop<128>(&sH[0][0], kc * 64, sW, r0, c0, acc);
    }

    // ---- bias + LN + residual write ----
    {
        const f4 b30 = *(const f4*)&b3[c0];
        const f4 b31 = *(const f4*)&b3[c0 + 4];
        const float bv[8] = {b30.x, b30.y, b30.z, b30.w,
                             b31.x, b31.y, b31.z, b31.w};
        const f4 g0 = *(const f4*)&gam[c0];
        const f4 g1 = *(const f4*)&gam[c0 + 4];
        const float gv[8] = {g0.x, g0.y, g0.z, g0.w, g1.x, g1.y, g1.z, g1.w};
        const f4 be0 = *(const f4*)&bet[c0];
        const f4 be1 = *(const f4*)&bet[c0 + 4];
        const float ev[8] = {be0.x, be0.y, be0.z, be0.w,
                             be1.x, be1.y, be1.z, be1.w};

#pragma unroll
        for (int i = 0; i < 4; ++i) {
            float h[8];
            float s = 0.f, ss = 0.f;
#pragma unroll
            for (int j = 0; j < 8; ++j) {
                h[j] = acc[i][j] + bv[j];
                s += h[j];
                ss = fmaf(h[j], h[j], ss);
            }
#pragma unroll
            for (int m = 1; m < 16; m <<= 1) {
                s  += __shfl_xor(s, m, 64);
                ss += __shfl_xor(ss, m, 64);
            }
            const float mu   = s * (1.f / 128.f);
            const float var  = ss * (1.f / 128.f) - mu * mu;
            const float rstd = rsqrtf(var + 1e-6f);

            const int n = n0 + r0 + i;
            if (n < N_NODES) {
                const f4 nr0 = *(const f4*)&nf[(size_t)n * D + c0];
                const f4 nr1 = *(const f4*)&nf[(size_t)n * D + c0 + 4];
                f4 o0, o1;
                o0.x = (h[0] - mu) * rstd * gv[0] + ev[0] + nr0.x;
                o0.y = (h[1] - mu) * rstd * gv[1] + ev[1] + nr0.y;
                o0.z = (h[2] - mu) * rstd * gv[2] + ev[2] + nr0.z;
                o0.w = (h[3] - mu) * rstd * gv[3] + ev[3] + nr0.w;
                o1.x = (h[4] - mu) * rstd * gv[4] + ev[4] + nr1.x;
                o1.y = (h[5] - mu) * rstd * gv[5] + ev[5] + nr1.y;
                o1.z = (h[6] - mu) * rstd * gv[6] + ev[6] + nr1.z;
                o1.w = (h[7] - mu) * rstd * gv[7] + ev[7] + nr1.w;
                *(f4*)&node_out[(size_t)n * D + c0]     = o0;
                *(f4*)&node_out[(size_t)n * D + c0 + 4] = o1;
            }
        }
    }
}

extern "C" void kernel_launch(void* const* d_in, const int* in_sizes, int n_in,
                              void* d_out, int out_size, void* d_ws, size_t ws_size,
                              hipStream_t stream) {
    const float* nf  = (const float*)d_in[0];
    const float* ef  = (const float*)d_in[1];
    const int*   snd = (const int*)d_in[2];
    const int*   rcv = (const int*)d_in[3];
    const float* We1 = (const float*)d_in[4];
    const float* be1 = (const float*)d_in[5];
    const float* We2 = (const float*)d_in[6];
    const float* be2 = (const float*)d_in[7];
    const float* We3 = (const float*)d_in[8];
    const float* be3 = (const float*)d_in[9];
    const float* ge  = (const float*)d_in[10];
    const float* Be  = (const float*)d_in[11];
    const float* Wn1 = (const float*)d_in[12];
    const float* bn1 = (const float*)d_in[13];
    const float* Wn2 = (const float*)d_in[14];
    const float* bn2 = (const float*)d_in[15];
    const float* Wn3 = (const float*)d_in[16];
    const float* bn3 = (const float*)d_in[17];
    const float* gn  = (const float*)d_in[18];
    const float* Bn  = (const float*)d_in[19];

    float* out      = (float*)d_out;
    float* node_out = out;                          // 50000*128
    float* edge_out = out + (size_t)N_NODES * D;    // 400000*128
    // agg is staged IN the node-output region of d_out (dead storage until
    // node_kernel's final write). d_ws is not used at all -> no dependence
    // on ws_size.
    float* agg = node_out;

    hipMemsetAsync(agg, 0, (size_t)N_NODES * D * sizeof(float), stream);

    edge_kernel<<<N_EDGES / TM, 256, 0, stream>>>(
        nf, ef, snd, rcv, We1, be1, We2, be2, We3, be3, ge, Be, edge_out, agg);

    node_kernel<<<(N_NODES + TM - 1) / TM, 256, 0, stream>>>(
        nf, agg, Wn1, bn1, Wn2, bn2, Wn3, bn3, gn, Bn, node_out);
}

// Round 5
// 1579.374 us; speedup vs baseline: 1.3367x; 1.3367x over previous
//
#include <hip/hip_runtime.h>
#include <math.h>

#define N_NODES 50000
#define N_EDGES 400000
#define D 128
#define TM 64   // rows (edges/nodes) per block

using f4 = float4;

// XOR swizzle for A-tiles (sX/sH), float4-granular:
// logical (row r, float-col fc, fc%4==0) -> physical float-col.
// Rows {i,i+4,i+8,i+12} get 4 distinct bank quads -> conflict-free reads.
__device__ __forceinline__ int swz4(int r, int fc) {
    return (((fc >> 2) ^ ((r >> 2) & 3)) << 2);
}

// Stage a 64x128 fp32 weight chunk into LDS (linear, no swizzle).
__device__ __forceinline__ void stage_w(const float* __restrict__ W,
                                        float (*sW)[128], int t) {
    const f4* s4 = (const f4*)W;
    f4* d4 = (f4*)&sW[0][0];
#pragma unroll
    for (int i = 0; i < 8; ++i) d4[t + i * 256] = s4[t + i * 256];
}

// 64-step K inner product, 4 k-steps/iter, float4 LDS loads both sides.
// A from sA (row-major, SA_STRIDE floats, XOR-swizzled). B from sW (linear).
// Thread owns rows r0..r0+3, cols c0a..c0a+3 and c0a+64..c0a+67.
template <int SA_STRIDE>
__device__ __forceinline__ void kloop(const float* __restrict__ sA, int a_col0,
                                      const float (*sW)[128],
                                      int r0, int c0a, float acc[4][8]) {
#pragma unroll 2
    for (int k = 0; k < 64; k += 4) {
        f4 av[4];
#pragma unroll
        for (int i = 0; i < 4; ++i) {
            const int r = r0 + i;
            av[i] = *(const f4*)&sA[r * SA_STRIDE + swz4(r, a_col0 + k)];
        }
        float bv[4][8];
#pragma unroll
        for (int kk = 0; kk < 4; ++kk) {
            const f4 b0 = *(const f4*)&sW[k + kk][c0a];
            const f4 b1 = *(const f4*)&sW[k + kk][c0a + 64];
            bv[kk][0] = b0.x; bv[kk][1] = b0.y; bv[kk][2] = b0.z; bv[kk][3] = b0.w;
            bv[kk][4] = b1.x; bv[kk][5] = b1.y; bv[kk][6] = b1.z; bv[kk][7] = b1.w;
        }
#pragma unroll
        for (int kk = 0; kk < 4; ++kk) {
            const float a0 = ((const float*)&av[0])[kk];
            const float a1 = ((const float*)&av[1])[kk];
            const float a2 = ((const float*)&av[2])[kk];
            const float a3 = ((const float*)&av[3])[kk];
#pragma unroll
            for (int j = 0; j < 8; ++j) {
                acc[0][j] = fmaf(a0, bv[kk][j], acc[0][j]);
                acc[1][j] = fmaf(a1, bv[kk][j], acc[1][j]);
                acc[2][j] = fmaf(a2, bv[kk][j], acc[2][j]);
                acc[3][j] = fmaf(a3, bv[kk][j], acc[3][j]);
            }
        }
    }
}

__device__ __forceinline__ void zero_acc(float acc[4][8]) {
#pragma unroll
    for (int i = 0; i < 4; ++i)
#pragma unroll
        for (int j = 0; j < 8; ++j) acc[i][j] = 0.f;
}

// bias + relu -> sH (swizzled writes)
__device__ __forceinline__ void bias_relu_to_sH(const float* __restrict__ b,
                                                float acc[4][8],
                                                float (*sH)[128],
                                                int r0, int c0a) {
    const f4 bb0 = *(const f4*)&b[c0a];
    const f4 bb1 = *(const f4*)&b[c0a + 64];
    const float bv[8] = {bb0.x, bb0.y, bb0.z, bb0.w,
                         bb1.x, bb1.y, bb1.z, bb1.w};
#pragma unroll
    for (int i = 0; i < 4; ++i) {
        const int r = r0 + i;
        f4 o0, o1;
        o0.x = fmaxf(acc[i][0] + bv[0], 0.f);
        o0.y = fmaxf(acc[i][1] + bv[1], 0.f);
        o0.z = fmaxf(acc[i][2] + bv[2], 0.f);
        o0.w = fmaxf(acc[i][3] + bv[3], 0.f);
        o1.x = fmaxf(acc[i][4] + bv[4], 0.f);
        o1.y = fmaxf(acc[i][5] + bv[5], 0.f);
        o1.z = fmaxf(acc[i][6] + bv[6], 0.f);
        o1.w = fmaxf(acc[i][7] + bv[7], 0.f);
        *(f4*)&sH[r][swz4(r, c0a)]      = o0;
        *(f4*)&sH[r][swz4(r, c0a + 64)] = o1;
    }
}

// ---------------- CSR build kernels ----------------
__global__ void hist_kernel(const int* __restrict__ rcv, int* __restrict__ deg) {
    const int e = blockIdx.x * 256 + threadIdx.x;
    if (e < N_EDGES) atomicAdd(&deg[rcv[e]], 1);
}

__global__ void scan_kernel(const int* __restrict__ deg, int* __restrict__ ptr,
                            int* __restrict__ cursor) {
    __shared__ int ssum[256];
    const int t  = threadIdx.x;
    const int CH = (N_NODES + 255) / 256;          // 196
    const int lo = t * CH;
    const int hi = (lo + CH < N_NODES) ? lo + CH : N_NODES;
    int s = 0;
    for (int i = lo; i < hi; ++i) s += deg[i];
    ssum[t] = s;
    __syncthreads();
    if (t == 0) {                                  // serial excl-scan of 256 ints
        int run = 0;
        for (int i = 0; i < 256; ++i) { const int d = ssum[i]; ssum[i] = run; run += d; }
    }
    __syncthreads();
    int base = ssum[t];
    for (int i = lo; i < hi; ++i) {
        ptr[i] = base; cursor[i] = base; base += deg[i];
    }
    if (hi == N_NODES && lo < N_NODES) ptr[N_NODES] = base;   // total = N_EDGES
}

__global__ void scatter_kernel(const int* __restrict__ rcv,
                               int* __restrict__ cursor, int* __restrict__ eidx) {
    const int e = blockIdx.x * 256 + threadIdx.x;
    if (e < N_EDGES) {
        const int p = atomicAdd(&cursor[rcv[e]], 1);
        eidx[p] = e;
    }
}

// ---------------- edge kernel ----------------
// edge_in = [nf[snd], nf[rcv], ef]  (K=384) -> 128 relu -> 128 relu -> 128
// -> LN -> write (LN + ef) to edge_out. If agg != nullptr (fallback path),
// also atomicAdd the pre-residual LN output into agg[rcv].
__global__ __launch_bounds__(256, 2)
void edge_kernel(const float* __restrict__ nf, const float* __restrict__ ef,
                 const int* __restrict__ snd, const int* __restrict__ rcv,
                 const float* __restrict__ W1, const float* __restrict__ b1,
                 const float* __restrict__ W2, const float* __restrict__ b2,
                 const float* __restrict__ W3, const float* __restrict__ b3,
                 const float* __restrict__ gam, const float* __restrict__ bet,
                 float* __restrict__ edge_out, float* __restrict__ agg) {
    __shared__ float sX[TM][64];    // 16 KiB  (layer-1 A chunk, swizzled)
    __shared__ float sW[64][128];   // 32 KiB  (weight chunk, linear)
    __shared__ float sH[TM][128];   // 32 KiB  (hidden activations, swizzled)

    const int t   = threadIdx.x;
    const int r0  = (t >> 4) * 4;   // thread's first row
    const int c0a = (t & 15) * 4;   // thread's cols: c0a+0..3 and c0a+64..67
    const int e0  = blockIdx.x * TM;

    const int ms = t >> 2;          // staging row (4 threads per row)
    const int kq = (t & 3) * 4;     // staging f4-quad base (of 16 per row)

    float acc[4][8];
    zero_acc(acc);

    // ---- layer 1: K=384 in 6 chunks of 64 ----
    for (int kc = 0; kc < 6; ++kc) {
        __syncthreads();            // prev kloop's sX/sW reads done
        stage_w(W1 + (size_t)kc * 64 * 128, sW, t);
        {
            const int e = e0 + ms;
            const float* src;
            if (kc < 2)      src = nf + (size_t)snd[e] * D + kc * 64;
            else if (kc < 4) src = nf + (size_t)rcv[e] * D + (kc - 2) * 64;
            else             src = ef + (size_t)e * D + (kc - 4) * 64;
            const int g = (ms >> 2) & 3;
#pragma unroll
            for (int i = 0; i < 4; ++i) {
                const f4 x = *(const f4*)&src[(kq + i) * 4];
                *(f4*)&sX[ms][((kq + i) ^ g) << 2] = x;
            }
        }
        __syncthreads();
        kloop<64>(&sX[0][0], 0, sW, r0, c0a, acc);
    }
    bias_relu_to_sH(b1, acc, sH, r0, c0a);

    // ---- layer 2: K=128, 2 chunks ----
    zero_acc(acc);
    for (int kc = 0; kc < 2; ++kc) {
        __syncthreads();            // sH writes visible / prev sW reads done
        stage_w(W2 + (size_t)kc * 64 * 128, sW, t);
        __syncthreads();
        kloop<128>(&sH[0][0], kc * 64, sW, r0, c0a, acc);
    }
    __syncthreads();                // all sH reads done before overwrite
    bias_relu_to_sH(b2, acc, sH, r0, c0a);

    // ---- layer 3: K=128, 2 chunks, linear ----
    zero_acc(acc);
    for (int kc = 0; kc < 2; ++kc) {
        __syncthreads();
        stage_w(W3 + (size_t)kc * 64 * 128, sW, t);
        __syncthreads();
        kloop<128>(&sH[0][0], kc * 64, sW, r0, c0a, acc);
    }

    // ---- bias + LayerNorm + residual write (+ fallback atomics) ----
    {
        const f4 b30 = *(const f4*)&b3[c0a];
        const f4 b31 = *(const f4*)&b3[c0a + 64];
        const float bv[8] = {b30.x, b30.y, b30.z, b30.w,
                             b31.x, b31.y, b31.z, b31.w};
        const f4 g0 = *(const f4*)&gam[c0a];
        const f4 g1 = *(const f4*)&gam[c0a + 64];
        const float gv[8] = {g0.x, g0.y, g0.z, g0.w, g1.x, g1.y, g1.z, g1.w};
        const f4 be0 = *(const f4*)&bet[c0a];
        const f4 be1 = *(const f4*)&bet[c0a + 64];
        const float ev[8] = {be0.x, be0.y, be0.z, be0.w,
                             be1.x, be1.y, be1.z, be1.w};

#pragma unroll
        for (int i = 0; i < 4; ++i) {
            float h[8];
            float s = 0.f, ss = 0.f;
#pragma unroll
            for (int j = 0; j < 8; ++j) {
                h[j] = acc[i][j] + bv[j];
                s += h[j];
                ss = fmaf(h[j], h[j], ss);
            }
            // reduce across the 16 lanes holding this row
#pragma unroll
            for (int m = 1; m < 16; m <<= 1) {
                s  += __shfl_xor(s, m, 64);
                ss += __shfl_xor(ss, m, 64);
            }
            const float mu   = s * (1.f / 128.f);
            const float var  = ss * (1.f / 128.f) - mu * mu;
            const float rstd = rsqrtf(var + 1e-6f);

            const int e = e0 + r0 + i;
            float v[8];
#pragma unroll
            for (int j = 0; j < 8; ++j)
                v[j] = (h[j] - mu) * rstd * gv[j] + ev[j];
            if (agg) {              // fallback path only (ws too small for CSR)
                const int dst = rcv[e];
#pragma unroll
                for (int j = 0; j < 8; ++j) {
                    const int col = c0a + ((j < 4) ? j : (60 + j));
                    atomicAdd(&agg[(size_t)dst * D + col], v[j]);
                }
            }
            const f4 er0 = *(const f4*)&ef[(size_t)e * D + c0a];
            const f4 er1 = *(const f4*)&ef[(size_t)e * D + c0a + 64];
            f4 o0, o1;
            o0.x = v[0] + er0.x; o0.y = v[1] + er0.y;
            o0.z = v[2] + er0.z; o0.w = v[3] + er0.w;
            o1.x = v[4] + er1.x; o1.y = v[5] + er1.y;
            o1.z = v[6] + er1.z; o1.w = v[7] + er1.w;
            *(f4*)&edge_out[(size_t)e * D + c0a]      = o0;
            *(f4*)&edge_out[(size_t)e * D + c0a + 64] = o1;
        }
    }
}

// ---------------- node kernel ----------------
// node_in = [nf, agg] (K=256) -> 128 relu -> 128 relu -> 128 -> LN
// -> write (LN + nf) to node_out.
// CSR mode (ptr != nullptr): agg tile computed in-kernel into sH (swizzled)
//   by gathering (edge_out[e] - ef[e]) over CSR edges.
// Fallback mode: agg read from global array (aliases node_out region).
__global__ __launch_bounds__(256, 2)
void node_kernel(const float* __restrict__ nf, const float* __restrict__ eo,
                 const float* __restrict__ ef,
                 const int* __restrict__ ptr, const int* __restrict__ eidx,
                 const float* __restrict__ agg,
                 const float* __restrict__ W1, const float* __restrict__ b1,
                 const float* __restrict__ W2, const float* __restrict__ b2,
                 const float* __restrict__ W3, const float* __restrict__ b3,
                 const float* __restrict__ gam, const float* __restrict__ bet,
                 float* __restrict__ node_out) {
    __shared__ float sX[TM][64];
    __shared__ float sW[64][128];
    __shared__ float sH[TM][128];

    const int t   = threadIdx.x;
    const int r0  = (t >> 4) * 4;
    const int c0a = (t & 15) * 4;
    const int n0  = blockIdx.x * TM;

    const int ms = t >> 2;
    const int kq = (t & 3) * 4;

    // ---- CSR gather prologue: agg tile -> sH (swizzled) ----
    if (ptr) {
        const int row = t >> 2;          // 0..63
        const int cc  = (t & 3) * 32;    // 32-col chunk per thread
        float a[32];
#pragma unroll
        for (int i = 0; i < 32; ++i) a[i] = 0.f;
        const int n = n0 + row;
        if (n < N_NODES) {
            const int jb = ptr[n], je = ptr[n + 1];
            for (int j = jb; j < je; ++j) {
                const int e = eidx[j];
                const float* es = eo + (size_t)e * D + cc;
                const float* rs = ef + (size_t)e * D + cc;
#pragma unroll
                for (int q = 0; q < 8; ++q) {
                    const f4 x = *(const f4*)&es[q * 4];
                    const f4 y = *(const f4*)&rs[q * 4];
                    a[q * 4 + 0] += x.x - y.x;
                    a[q * 4 + 1] += x.y - y.y;
                    a[q * 4 + 2] += x.z - y.z;
                    a[q * 4 + 3] += x.w - y.w;
                }
            }
        }
#pragma unroll
        for (int q = 0; q < 8; ++q)
            *(f4*)&sH[row][swz4(row, cc + q * 4)] =
                make_float4(a[q * 4], a[q * 4 + 1], a[q * 4 + 2], a[q * 4 + 3]);
    }
    // (visibility of sH ensured by the barrier at top of each chunk below)

    float acc[4][8];
    zero_acc(acc);

    // ---- layer 1: K=256, 4 chunks of 64 ----
    for (int kc = 0; kc < 4; ++kc) {
        __syncthreads();
        stage_w(W1 + (size_t)kc * 64 * 128, sW, t);
        const bool fromX = ptr ? (kc < 2) : true;
        if (fromX) {
            int n = n0 + ms;
            if (n >= N_NODES) n = N_NODES - 1;   // clamp (last block only)
            const float* src;
            if (ptr) src = nf + (size_t)n * D + kc * 64;
            else     src = (kc < 2) ? nf  + (size_t)n * D + kc * 64
                                    : agg + (size_t)n * D + (kc - 2) * 64;
            const int g = (ms >> 2) & 3;
#pragma unroll
            for (int i = 0; i < 4; ++i) {
                const f4 x = *(const f4*)&src[(kq + i) * 4];
                *(f4*)&sX[ms][((kq + i) ^ g) << 2] = x;
            }
        }
        __syncthreads();
        if (fromX) kloop<64>(&sX[0][0], 0, sW, r0, c0a, acc);
        else       kloop<128>(&sH[0][0], (kc - 2) * 64, sW, r0, c0a, acc);
    }
    __syncthreads();                 // all sH (agg) reads done before overwrite
    bias_relu_to_sH(b1, acc, sH, r0, c0a);

    // ---- layer 2 ----
    zero_acc(acc);
    for (int kc = 0; kc < 2; ++kc) {
        __syncthreads();
        stage_w(W2 + (size_t)kc * 64 * 128, sW, t);
        __syncthreads();
        kloop<128>(&sH[0][0], kc * 64, sW, r0, c0a, acc);
    }
    __syncthreads();
    bias_relu_to_sH(b2, acc, sH, r0, c0a);

    // ---- layer 3 ----
    zero_acc(acc);
    for (int kc = 0; kc < 2; ++kc) {
        __syncthreads();
        stage_w(W3 + (size_t)kc * 64 * 128, sW, t);
        __syncthreads();
        kloop<128>(&sH[0][0], kc * 64, sW, r0, c0a, acc);
    }

    // ---- bias + LN + residual write ----
    {
        const f4 b30 = *(const f4*)&b3[c0a];
        const f4 b31 = *(const f4*)&b3[c0a + 64];
        const float bv[8] = {b30.x, b30.y, b30.z, b30.w,
                             b31.x, b31.y, b31.z, b31.w};
        const f4 g0 = *(const f4*)&gam[c0a];
        const f4 g1 = *(const f4*)&gam[c0a + 64];
        const float gv[8] = {g0.x, g0.y, g0.z, g0.w, g1.x, g1.y, g1.z, g1.w};
        const f4 be0 = *(const f4*)&bet[c0a];
        const f4 be1 = *(const f4*)&bet[c0a + 64];
        const float ev[8] = {be0.x, be0.y, be0.z, be0.w,
                             be1.x, be1.y, be1.z, be1.w};

#pragma unroll
        for (int i = 0; i < 4; ++i) {
            float h[8];
            float s = 0.f, ss = 0.f;
#pragma unroll
            for (int j = 0; j < 8; ++j) {
                h[j] = acc[i][j] + bv[j];
                s += h[j];
                ss = fmaf(h[j], h[j], ss);
            }
#pragma unroll
            for (int m = 1; m < 16; m <<= 1) {
                s  += __shfl_xor(s, m, 64);
                ss += __shfl_xor(ss, m, 64);
            }
            const float mu   = s * (1.f / 128.f);
            const float var  = ss * (1.f / 128.f) - mu * mu;
            const float rstd = rsqrtf(var + 1e-6f);

            const int n = n0 + r0 + i;
            if (n < N_NODES) {
                const f4 nr0 = *(const f4*)&nf[(size_t)n * D + c0a];
                const f4 nr1 = *(const f4*)&nf[(size_t)n * D + c0a + 64];
                f4 o0, o1;
                o0.x = (h[0] - mu) * rstd * gv[0] + ev[0] + nr0.x;
                o0.y = (h[1] - mu) * rstd * gv[1] + ev[1] + nr0.y;
                o0.z = (h[2] - mu) * rstd * gv[2] + ev[2] + nr0.z;
                o0.w = (h[3] - mu) * rstd * gv[3] + ev[3] + nr0.w;
                o1.x = (h[4] - mu) * rstd * gv[4] + ev[4] + nr1.x;
                o1.y = (h[5] - mu) * rstd * gv[5] + ev[5] + nr1.y;
                o1.z = (h[6] - mu) * rstd * gv[6] + ev[6] + nr1.z;
                o1.w = (h[7] - mu) * rstd * gv[7] + ev[7] + nr1.w;
                *(f4*)&node_out[(size_t)n * D + c0a]      = o0;
                *(f4*)&node_out[(size_t)n * D + c0a + 64] = o1;
            }
        }
    }
}

extern "C" void kernel_launch(void* const* d_in, const int* in_sizes, int n_in,
                              void* d_out, int out_size, void* d_ws, size_t ws_size,
                              hipStream_t stream) {
    const float* nf  = (const float*)d_in[0];
    const float* ef  = (const float*)d_in[1];
    const int*   snd = (const int*)d_in[2];
    const int*   rcv = (const int*)d_in[3];
    const float* We1 = (const float*)d_in[4];
    const float* be1 = (const float*)d_in[5];
    const float* We2 = (const float*)d_in[6];
    const float* be2 = (const float*)d_in[7];
    const float* We3 = (const float*)d_in[8];
    const float* be3 = (const float*)d_in[9];
    const float* ge  = (const float*)d_in[10];
    const float* Be  = (const float*)d_in[11];
    const float* Wn1 = (const float*)d_in[12];
    const float* bn1 = (const float*)d_in[13];
    const float* Wn2 = (const float*)d_in[14];
    const float* bn2 = (const float*)d_in[15];
    const float* Wn3 = (const float*)d_in[16];
    const float* bn3 = (const float*)d_in[17];
    const float* gn  = (const float*)d_in[18];
    const float* Bn  = (const float*)d_in[19];

    float* out      = (float*)d_out;
    float* node_out = out;                          // 50000*128
    float* edge_out = out + (size_t)N_NODES * D;    // 400000*128

    const size_t csr_bytes = (size_t)(N_NODES * 2 + (N_NODES + 1) + N_EDGES) * 4;

    if (ws_size >= csr_bytes) {
        // ---- CSR path: no fp32 atomics ----
        int* deg    = (int*)d_ws;            // 50000
        int* ptr    = deg + N_NODES;         // 50001
        int* cursor = ptr + N_NODES + 1;     // 50000
        int* eidx   = cursor + N_NODES;      // 400000

        hipMemsetAsync(deg, 0, (size_t)N_NODES * sizeof(int), stream);
        hist_kernel<<<(N_EDGES + 255) / 256, 256, 0, stream>>>(rcv, deg);
        scan_kernel<<<1, 256, 0, stream>>>(deg, ptr, cursor);
        scatter_kernel<<<(N_EDGES + 255) / 256, 256, 0, stream>>>(rcv, cursor, eidx);

        edge_kernel<<<N_EDGES / TM, 256, 0, stream>>>(
            nf, ef, snd, rcv, We1, be1, We2, be2, We3, be3, ge, Be,
            edge_out, nullptr);

        node_kernel<<<(N_NODES + TM - 1) / TM, 256, 0, stream>>>(
            nf, edge_out, ef, ptr, eidx, nullptr,
            Wn1, bn1, Wn2, bn2, Wn3, bn3, gn, Bn, node_out);
    } else {
        // ---- fallback: verified atomic path (agg staged in node_out region) ----
        float* agg = node_out;
        hipMemsetAsync(agg, 0, (size_t)N_NODES * D * sizeof(float), stream);

        edge_kernel<<<N_EDGES / TM, 256, 0, stream>>>(
            nf, ef, snd, rcv, We1, be1, We2, be2, We3, be3, ge, Be,
            edge_out, agg);

        node_kernel<<<(N_NODES + TM - 1) / TM, 256, 0, stream>>>(
            nf, edge_out, ef, nullptr, nullptr, agg,
            Wn1, bn1, Wn2, bn2, Wn3, bn3, gn, Bn, node_out);
    }
}

// Round 8
// 842.843 us; speedup vs baseline: 2.5049x; 1.8739x over previous
//
#include <hip/hip_runtime.h>
#include <math.h>

#define N_NODES 50000
#define N_EDGES 400000
#define D 128
#define TM 64   // rows (edges/nodes) per block

using f4 = float4;
typedef _Float16 h8 __attribute__((ext_vector_type(8)));
typedef _Float16 h4 __attribute__((ext_vector_type(4)));
typedef float f32x4 __attribute__((ext_vector_type(4)));

// ============================================================================
//  MFMA path (fp16 inputs, fp32 accumulate), swapped-operand scheme:
//  compute H^T = W * X  with  A-operand = W^T tiles, B-operand = activations.
//  D[m=out_feature][n=edge];  C/D map (HW-verified): n = lane&15,
//  m = 4*(lane>>4) + reg.  A/B frags: row/col = lane&15, k = 8*(lane>>4)+j.
//  LDS activation tiles are [row][feat] fp16 with 16B-unit XOR swizzle:
//  unit' = unit ^ (row & 7)  (2-way conflicts max).  Weight tiles are
//  pre-swizzled in d_ws by prep_w so staging is a linear copy.
// ============================================================================

// fragment read from an activation tile: row-major [row][rowu*8] fp16
__device__ __forceinline__ h8 lds_frag(const _Float16* base, int row, int rowu, int u) {
    return *(const h8*)(base + row * rowu * 8 + ((u ^ (row & 7)) << 3));
}
// fragment read from a weight tile (row-len 8 units, pre-swizzled)
__device__ __forceinline__ h8 w_frag(const _Float16* sw, int n, int u) {
    return *(const h8*)(sw + n * 64 + ((u ^ (n & 7)) << 3));
}

// one 64-k chunk = 2 MFMA K-steps. act: activation tile, rowu units/row,
// ubase: unit offset of this chunk inside the activation tile.
__device__ __forceinline__ void mfma_chunk(const _Float16* act, int rowu, int ubase,
                                           const _Float16* sw,
                                           int fw, int ew, int lm, int lg,
                                           f32x4 acc[4][2]) {
#pragma unroll
    for (int ks = 0; ks < 2; ++ks) {
        const int uw = ks * 4 + lg;          // unit within weight chunk [0,8)
        const int ua = ubase + uw;           // unit within activation tile
        h8 Bf[2], Af[4];
#pragma unroll
        for (int j = 0; j < 2; ++j)
            Bf[j] = lds_frag(act, ew * 32 + j * 16 + lm, rowu, ua);
#pragma unroll
        for (int i = 0; i < 4; ++i)
            Af[i] = w_frag(sw, fw * 64 + i * 16 + lm, uw);
#pragma unroll
        for (int i = 0; i < 4; ++i)
#pragma unroll
            for (int j = 0; j < 2; ++j)
                acc[i][j] = __builtin_amdgcn_mfma_f32_16x16x32_f16(
                    Af[i], Bf[j], acc[i][j], 0, 0, 0);
    }
}

__device__ __forceinline__ void zero_acc2(f32x4 acc[4][2]) {
    const f32x4 z = {0.f, 0.f, 0.f, 0.f};
#pragma unroll
    for (int i = 0; i < 4; ++i)
#pragma unroll
        for (int j = 0; j < 2; ++j) acc[i][j] = z;
}

// bias + relu -> activation tile sH [64 rows][128 feats] fp16 (swizzled).
// Lane's 4 regs = 4 consecutive features at one edge -> one 8B store each.
__device__ __forceinline__ void epi_relu_store(f32x4 acc[4][2], const float* __restrict__ b,
                                               _Float16* sH, int fw, int ew, int lm, int lg) {
#pragma unroll
    for (int i = 0; i < 4; ++i) {
        const int f0 = fw * 64 + i * 16 + lg * 4;
        const f4 bb = *(const f4*)&b[f0];
#pragma unroll
        for (int j = 0; j < 2; ++j) {
            const int e = ew * 32 + j * 16 + lm;
            h4 v;
            v[0] = (_Float16)fmaxf(acc[i][j][0] + bb.x, 0.f);
            v[1] = (_Float16)fmaxf(acc[i][j][1] + bb.y, 0.f);
            v[2] = (_Float16)fmaxf(acc[i][j][2] + bb.z, 0.f);
            v[3] = (_Float16)fmaxf(acc[i][j][3] + bb.w, 0.f);
            const int u = f0 >> 3;
            *(h4*)(sH + e * 128 + ((u ^ (e & 7)) << 3) + (f0 & 7)) = v;
        }
    }
}

// ---------------- weight prep: fp32 [K][128] -> fp16 W^T tiles ----------------
// tile = [128 n][8 units] where stored unit `up` at row n holds source
// k-range [k0 + 8*(up^(n&7)), +8). 18 chunks total.
__global__ void prep_w(const float* __restrict__ We1, const float* __restrict__ We2,
                       const float* __restrict__ We3, const float* __restrict__ Wn1,
                       const float* __restrict__ Wn2, const float* __restrict__ Wn3,
                       _Float16* __restrict__ wtsE, _Float16* __restrict__ wtsN) {
    const int c = blockIdx.x;
    const float* W; int k0; _Float16* dst;
    if (c < 6)       { W = We1; k0 = c * 64;        dst = wtsE + c * 8192; }
    else if (c < 8)  { W = We2; k0 = (c - 6) * 64;  dst = wtsE + c * 8192; }
    else if (c < 10) { W = We3; k0 = (c - 8) * 64;  dst = wtsE + c * 8192; }
    else if (c < 14) { W = Wn1; k0 = (c - 10) * 64; dst = wtsN + (c - 10) * 8192; }
    else if (c < 16) { W = Wn2; k0 = (c - 14) * 64; dst = wtsN + (c - 10) * 8192; }
    else             { W = Wn3; k0 = (c - 16) * 64; dst = wtsN + (c - 10) * 8192; }
    for (int idx = threadIdx.x; idx < 1024; idx += 256) {
        const int n = idx >> 3, up = idx & 7;
        const int kb = k0 + ((up ^ (n & 7)) << 3);
        h8 v;
#pragma unroll
        for (int x = 0; x < 8; ++x) v[x] = (_Float16)W[(size_t)(kb + x) * 128 + n];
        *(h8*)&dst[idx * 8] = v;
    }
}

// ---------------- CSR build kernels ----------------
__global__ void hist_kernel(const int* __restrict__ rcv, int* __restrict__ deg) {
    const int e = blockIdx.x * 256 + threadIdx.x;
    if (e < N_EDGES) atomicAdd(&deg[rcv[e]], 1);
}

__global__ void scan_kernel(const int* __restrict__ deg, int* __restrict__ ptr,
                            int* __restrict__ cursor) {
    __shared__ int ssum[256];
    const int t  = threadIdx.x;
    const int CH = (N_NODES + 255) / 256;
    const int lo = t * CH;
    const int hi = (lo + CH < N_NODES) ? lo + CH : N_NODES;
    int s = 0;
    for (int i = lo; i < hi; ++i) s += deg[i];
    ssum[t] = s;
    __syncthreads();
    if (t == 0) {
        int run = 0;
        for (int i = 0; i < 256; ++i) { const int d = ssum[i]; ssum[i] = run; run += d; }
    }
    __syncthreads();
    int base = ssum[t];
    for (int i = lo; i < hi; ++i) {
        ptr[i] = base; cursor[i] = base; base += deg[i];
    }
    if (hi == N_NODES && lo < N_NODES) ptr[N_NODES] = base;
}

__global__ void scatter_kernel(const int* __restrict__ rcv,
                               int* __restrict__ cursor, int* __restrict__ eidx) {
    const int e = blockIdx.x * 256 + threadIdx.x;
    if (e < N_EDGES) {
        const int p = atomicAdd(&cursor[rcv[e]], 1);
        eidx[p] = e;
    }
}

// ---------------- MFMA edge kernel ----------------
// [nf[snd], nf[rcv], ef] (K=384) -> 128 relu -> 128 relu -> 128 -> LN
// -> edge_out = LN + ef
__global__ __launch_bounds__(256, 4)
void edge_mfma(const float* __restrict__ nf, const float* __restrict__ ef,
               const int* __restrict__ snd, const int* __restrict__ rcv,
               const _Float16* __restrict__ wtsE,
               const float* __restrict__ b1, const float* __restrict__ b2,
               const float* __restrict__ b3,
               const float* __restrict__ gam, const float* __restrict__ bet,
               float* __restrict__ edge_out) {
    __shared__ _Float16 sX[64 * 64];     //  8 KB layer-1 activation chunk
    __shared__ _Float16 sW[128 * 64];    // 16 KB weight chunk
    __shared__ _Float16 sH[64 * 128];    // 16 KB hidden activations

    const int t  = threadIdx.x;
    const int l  = t & 63;
    const int wv = t >> 6;
    const int fw = wv >> 1;       // feature half  [64*fw, +64)
    const int ew = wv & 1;        // edge half     [32*ew, +32)
    const int lm = l & 15;
    const int lg = (l >> 4) & 3;
    const int e0 = blockIdx.x * TM;

    f32x4 acc[4][2];
    zero_acc2(acc);

    // ---- layer 1: K=384, 6 chunks ----
    for (int kc = 0; kc < 6; ++kc) {
        __syncthreads();
        {   // stage weight chunk (linear, pre-swizzled)
            const f4* s4 = (const f4*)(wtsE + kc * 8192);
            f4* d4 = (f4*)sW;
#pragma unroll
            for (int i = 0; i < 4; ++i) d4[t + i * 256] = s4[t + i * 256];
        }
        {   // stage gathered activation chunk -> sX fp16 swizzled
            const int row = t >> 2;
            const int e = e0 + row;
            const float* src;
            if (kc < 2)      src = nf + (size_t)snd[e] * D + kc * 64;
            else if (kc < 4) src = nf + (size_t)rcv[e] * D + (kc - 2) * 64;
            else             src = ef + (size_t)e * D + (kc - 4) * 64;
#pragma unroll
            for (int ii = 0; ii < 2; ++ii) {
                const int u = (t & 3) * 2 + ii;
                const f4 a = *(const f4*)&src[u * 8];
                const f4 b = *(const f4*)&src[u * 8 + 4];
                h8 v;
                v[0] = (_Float16)a.x; v[1] = (_Float16)a.y;
                v[2] = (_Float16)a.z; v[3] = (_Float16)a.w;
                v[4] = (_Float16)b.x; v[5] = (_Float16)b.y;
                v[6] = (_Float16)b.z; v[7] = (_Float16)b.w;
                *(h8*)&sX[row * 64 + ((u ^ (row & 7)) << 3)] = v;
            }
        }
        __syncthreads();
        mfma_chunk(sX, 8, 0, sW, fw, ew, lm, lg, acc);
    }
    __syncthreads();
    epi_relu_store(acc, b1, sH, fw, ew, lm, lg);

    // ---- layer 2: K=128, 2 chunks ----
    zero_acc2(acc);
    for (int kc = 0; kc < 2; ++kc) {
        __syncthreads();
        const f4* s4 = (const f4*)(wtsE + (6 + kc) * 8192);
        f4* d4 = (f4*)sW;
#pragma unroll
        for (int i = 0; i < 4; ++i) d4[t + i * 256] = s4[t + i * 256];
        __syncthreads();
        mfma_chunk(sH, 16, kc * 8, sW, fw, ew, lm, lg, acc);
    }
    __syncthreads();
    epi_relu_store(acc, b2, sH, fw, ew, lm, lg);

    // ---- layer 3: K=128, 2 chunks ----
    zero_acc2(acc);
    for (int kc = 0; kc < 2; ++kc) {
        __syncthreads();
        const f4* s4 = (const f4*)(wtsE + (8 + kc) * 8192);
        f4* d4 = (f4*)sW;
#pragma unroll
        for (int i = 0; i < 4; ++i) d4[t + i * 256] = s4[t + i * 256];
        __syncthreads();
        mfma_chunk(sH, 16, kc * 8, sW, fw, ew, lm, lg, acc);
    }

    // ---- bias + LN (fp32) + residual write ----
    {
        float s[2] = {0.f, 0.f}, ss[2] = {0.f, 0.f};
#pragma unroll
        for (int i = 0; i < 4; ++i) {
            const int f0 = fw * 64 + i * 16 + lg * 4;
            const f4 bb = *(const f4*)&b3[f0];
#pragma unroll
            for (int j = 0; j < 2; ++j) {
                acc[i][j][0] += bb.x; acc[i][j][1] += bb.y;
                acc[i][j][2] += bb.z; acc[i][j][3] += bb.w;
#pragma unroll
                for (int r = 0; r < 4; ++r) {
                    s[j] += acc[i][j][r];
                    ss[j] = fmaf(acc[i][j][r], acc[i][j][r], ss[j]);
                }
            }
        }
#pragma unroll
        for (int m = 16; m < 64; m <<= 1) {
#pragma unroll
            for (int j = 0; j < 2; ++j) {
                s[j]  += __shfl_xor(s[j], m, 64);
                ss[j] += __shfl_xor(ss[j], m, 64);
            }
        }
        float* sLN = (float*)sX;          // sX dead after layer 1
        __syncthreads();
        if (lg == 0) {
#pragma unroll
            for (int j = 0; j < 2; ++j) {
                const int el = ew * 32 + j * 16 + lm;
                sLN[(el * 2 + fw) * 2 + 0] = s[j];
                sLN[(el * 2 + fw) * 2 + 1] = ss[j];
            }
        }
        __syncthreads();
#pragma unroll
        for (int j = 0; j < 2; ++j) {
            const int el = ew * 32 + j * 16 + lm;
            const float S  = sLN[(el * 2) * 2 + 0] + sLN[(el * 2 + 1) * 2 + 0];
            const float SS = sLN[(el * 2) * 2 + 1] + sLN[(el * 2 + 1) * 2 + 1];
            const float mu   = S * (1.f / 128.f);
            const float var  = SS * (1.f / 128.f) - mu * mu;
            const float rstd = rsqrtf(var + 1e-6f);
            const size_t e = (size_t)(e0 + el);
#pragma unroll
            for (int i = 0; i < 4; ++i) {
                const int f0 = fw * 64 + i * 16 + lg * 4;
                const f4 g  = *(const f4*)&gam[f0];
                const f4 be = *(const f4*)&bet[f0];
                const f4 er = *(const f4*)&ef[e * D + f0];
                f4 o;
                o.x = (acc[i][j][0] - mu) * rstd * g.x + be.x + er.x;
                o.y = (acc[i][j][1] - mu) * rstd * g.y + be.y + er.y;
                o.z = (acc[i][j][2] - mu) * rstd * g.z + be.z + er.z;
                o.w = (acc[i][j][3] - mu) * rstd * g.w + be.w + er.w;
                *(f4*)&edge_out[e * D + f0] = o;
            }
        }
    }
}

// ---------------- MFMA node kernel ----------------
// [nf, agg] (K=256) -> 128 relu -> 128 relu -> 128 -> LN -> node_out = LN + nf
// agg gathered via CSR from (edge_out - ef).
__global__ __launch_bounds__(256, 4)
void node_mfma(const float* __restrict__ nf, const float* __restrict__ eo,
               const float* __restrict__ ef,
               const int* __restrict__ ptr, const int* __restrict__ eidx,
               const _Float16* __restrict__ wtsN,
               const float* __restrict__ b1, const float* __restrict__ b2,
               const float* __restrict__ b3,
               const float* __restrict__ gam, const float* __restrict__ bet,
               float* __restrict__ node_out) {
    __shared__ _Float16 sX[64 * 64];
    __shared__ _Float16 sW[128 * 64];
    __shared__ _Float16 sH[64 * 128];

    const int t  = threadIdx.x;
    const int l  = t & 63;
    const int wv = t >> 6;
    const int fw = wv >> 1;
    const int ew = wv & 1;
    const int lm = l & 15;
    const int lg = (l >> 4) & 3;
    const int n0 = blockIdx.x * TM;

    // ---- CSR gather prologue: agg tile -> sH fp16 (swizzled) ----
    {
        const int row = t >> 2;
        const int cc  = (t & 3) * 32;
        float a[32];
#pragma unroll
        for (int i = 0; i < 32; ++i) a[i] = 0.f;
        const int n = n0 + row;
        if (n < N_NODES) {
            const int jb = ptr[n], je = ptr[n + 1];
            for (int j = jb; j < je; ++j) {
                const int e = eidx[j];
                const float* es = eo + (size_t)e * D + cc;
                const float* rs = ef + (size_t)e * D + cc;
#pragma unroll
                for (int q = 0; q < 8; ++q) {
                    const f4 x = *(const f4*)&es[q * 4];
                    const f4 y = *(const f4*)&rs[q * 4];
                    a[q * 4 + 0] += x.x - y.x;
                    a[q * 4 + 1] += x.y - y.y;
                    a[q * 4 + 2] += x.z - y.z;
                    a[q * 4 + 3] += x.w - y.w;
                }
            }
        }
#pragma unroll
        for (int q = 0; q < 4; ++q) {
            const int u = (cc >> 3) + q;
            h8 v;
#pragma unroll
            for (int x = 0; x < 8; ++x) v[x] = (_Float16)a[q * 8 + x];
            *(h8*)&sH[row * 128 + ((u ^ (row & 7)) << 3)] = v;
        }
    }

    f32x4 acc[4][2];
    zero_acc2(acc);

    // ---- layer 1: K=256, 4 chunks (0,1: nf via sX; 2,3: agg in sH) ----
    for (int kc = 0; kc < 4; ++kc) {
        __syncthreads();
        {
            const f4* s4 = (const f4*)(wtsN + kc * 8192);
            f4* d4 = (f4*)sW;
#pragma unroll
            for (int i = 0; i < 4; ++i) d4[t + i * 256] = s4[t + i * 256];
        }
        if (kc < 2) {
            int row = t >> 2;
            int n = n0 + row;
            if (n >= N_NODES) n = N_NODES - 1;
            const float* src = nf + (size_t)n * D + kc * 64;
#pragma unroll
            for (int ii = 0; ii < 2; ++ii) {
                const int u = (t & 3) * 2 + ii;
                const f4 a = *(const f4*)&src[u * 8];
                const f4 b = *(const f4*)&src[u * 8 + 4];
                h8 v;
                v[0] = (_Float16)a.x; v[1] = (_Float16)a.y;
                v[2] = (_Float16)a.z; v[3] = (_Float16)a.w;
                v[4] = (_Float16)b.x; v[5] = (_Float16)b.y;
                v[6] = (_Float16)b.z; v[7] = (_Float16)b.w;
                *(h8*)&sX[row * 64 + ((u ^ (row & 7)) << 3)] = v;
            }
        }
        __syncthreads();
        if (kc < 2) mfma_chunk(sX, 8, 0, sW, fw, ew, lm, lg, acc);
        else        mfma_chunk(sH, 16, (kc - 2) * 8, sW, fw, ew, lm, lg, acc);
    }
    __syncthreads();                 // agg reads done before sH overwrite
    epi_relu_store(acc, b1, sH, fw, ew, lm, lg);

    // ---- layer 2 ----
    zero_acc2(acc);
    for (int kc = 0; kc < 2; ++kc) {
        __syncthreads();
        const f4* s4 = (const f4*)(wtsN + (4 + kc) * 8192);
        f4* d4 = (f4*)sW;
#pragma unroll
        for (int i = 0; i < 4; ++i) d4[t + i * 256] = s4[t + i * 256];
        __syncthreads();
        mfma_chunk(sH, 16, kc * 8, sW, fw, ew, lm, lg, acc);
    }
    __syncthreads();
    epi_relu_store(acc, b2, sH, fw, ew, lm, lg);

    // ---- layer 3 ----
    zero_acc2(acc);
    for (int kc = 0; kc < 2; ++kc) {
        __syncthreads();
        const f4* s4 = (const f4*)(wtsN + (6 + kc) * 8192);
        f4* d4 = (f4*)sW;
#pragma unroll
        for (int i = 0; i < 4; ++i) d4[t + i * 256] = s4[t + i * 256];
        __syncthreads();
        mfma_chunk(sH, 16, kc * 8, sW, fw, ew, lm, lg, acc);
    }

    // ---- bias + LN + residual write ----
    {
        float s[2] = {0.f, 0.f}, ss[2] = {0.f, 0.f};
#pragma unroll
        for (int i = 0; i < 4; ++i) {
            const int f0 = fw * 64 + i * 16 + lg * 4;
            const f4 bb = *(const f4*)&b3[f0];
#pragma unroll
            for (int j = 0; j < 2; ++j) {
                acc[i][j][0] += bb.x; acc[i][j][1] += bb.y;
                acc[i][j][2] += bb.z; acc[i][j][3] += bb.w;
#pragma unroll
                for (int r = 0; r < 4; ++r) {
                    s[j] += acc[i][j][r];
                    ss[j] = fmaf(acc[i][j][r], acc[i][j][r], ss[j]);
                }
            }
        }
#pragma unroll
        for (int m = 16; m < 64; m <<= 1) {
#pragma unroll
            for (int j = 0; j < 2; ++j) {
                s[j]  += __shfl_xor(s[j], m, 64);
                ss[j] += __shfl_xor(ss[j], m, 64);
            }
        }
        float* sLN = (float*)sX;
        __syncthreads();
        if (lg == 0) {
#pragma unroll
            for (int j = 0; j < 2; ++j) {
                const int el = ew * 32 + j * 16 + lm;
                sLN[(el * 2 + fw) * 2 + 0] = s[j];
                sLN[(el * 2 + fw) * 2 + 1] = ss[j];
            }
        }
        __syncthreads();
#pragma unroll
        for (int j = 0; j < 2; ++j) {
            const int el = ew * 32 + j * 16 + lm;
            const int n = n0 + el;
            if (n < N_NODES) {
                const float S  = sLN[(el * 2) * 2 + 0] + sLN[(el * 2 + 1) * 2 + 0];
                const float SS = sLN[(el * 2) * 2 + 1] + sLN[(el * 2 + 1) * 2 + 1];
                const float mu   = S * (1.f / 128.f);
                const float var  = SS * (1.f / 128.f) - mu * mu;
                const float rstd = rsqrtf(var + 1e-6f);
#pragma unroll
                for (int i = 0; i < 4; ++i) {
                    const int f0 = fw * 64 + i * 16 + lg * 4;
                    const f4 g  = *(const f4*)&gam[f0];
                    const f4 be = *(const f4*)&bet[f0];
                    const f4 nr = *(const f4*)&nf[(size_t)n * D + f0];
                    f4 o;
                    o.x = (acc[i][j][0] - mu) * rstd * g.x + be.x + nr.x;
                    o.y = (acc[i][j][1] - mu) * rstd * g.y + be.y + nr.y;
                    o.z = (acc[i][j][2] - mu) * rstd * g.z + be.z + nr.z;
                    o.w = (acc[i][j][3] - mu) * rstd * g.w + be.w + nr.w;
                    *(f4*)&node_out[(size_t)n * D + f0] = o;
                }
            }
        }
    }
}

// ============================================================================
//  Verified fp32 fallback path (used only if d_ws is too small).
// ============================================================================
__device__ __forceinline__ int swz4(int r, int fc) {
    return (((fc >> 2) ^ ((r >> 2) & 3)) << 2);
}
__device__ __forceinline__ void stage_w32(const float* __restrict__ W,
                                          float (*sW)[128], int t) {
    const f4* s4 = (const f4*)W;
    f4* d4 = (f4*)&sW[0][0];
#pragma unroll
    for (int i = 0; i < 8; ++i) d4[t + i * 256] = s4[t + i * 256];
}
template <int SA_STRIDE>
__device__ __forceinline__ void kloop32(const float* __restrict__ sA, int a_col0,
                                        const float (*sW)[128],
                                        int r0, int c0a, float acc[4][8]) {
#pragma unroll 2
    for (int k = 0; k < 64; k += 4) {
        f4 av[4];
#pragma unroll
        for (int i = 0; i < 4; ++i) {
            const int r = r0 + i;
            av[i] = *(const f4*)&sA[r * SA_STRIDE + swz4(r, a_col0 + k)];
        }
        float bv[4][8];
#pragma unroll
        for (int kk = 0; kk < 4; ++kk) {
            const f4 b0 = *(const f4*)&sW[k + kk][c0a];
            const f4 b1 = *(const f4*)&sW[k + kk][c0a + 64];
            bv[kk][0] = b0.x; bv[kk][1] = b0.y; bv[kk][2] = b0.z; bv[kk][3] = b0.w;
            bv[kk][4] = b1.x; bv[kk][5] = b1.y; bv[kk][6] = b1.z; bv[kk][7] = b1.w;
        }
#pragma unroll
        for (int kk = 0; kk < 4; ++kk) {
            const float a0 = ((const float*)&av[0])[kk];
            const float a1 = ((const float*)&av[1])[kk];
            const float a2 = ((const float*)&av[2])[kk];
            const float a3 = ((const float*)&av[3])[kk];
#pragma unroll
            for (int j = 0; j < 8; ++j) {
                acc[0][j] = fmaf(a0, bv[kk][j], acc[0][j]);
                acc[1][j] = fmaf(a1, bv[kk][j], acc[1][j]);
                acc[2][j] = fmaf(a2, bv[kk][j], acc[2][j]);
                acc[3][j] = fmaf(a3, bv[kk][j], acc[3][j]);
            }
        }
    }
}
__device__ __forceinline__ void zero_acc32(float acc[4][8]) {
#pragma unroll
    for (int i = 0; i < 4; ++i)
#pragma unroll
        for (int j = 0; j < 8; ++j) acc[i][j] = 0.f;
}
__device__ __forceinline__ void bias_relu32(const float* __restrict__ b,
                                            float acc[4][8], float (*sH)[128],
                                            int r0, int c0a) {
    const f4 bb0 = *(const f4*)&b[c0a];
    const f4 bb1 = *(const f4*)&b[c0a + 64];
    const float bv[8] = {bb0.x, bb0.y, bb0.z, bb0.w, bb1.x, bb1.y, bb1.z, bb1.w};
#pragma unroll
    for (int i = 0; i < 4; ++i) {
        const int r = r0 + i;
        f4 o0, o1;
        o0.x = fmaxf(acc[i][0] + bv[0], 0.f);
        o0.y = fmaxf(acc[i][1] + bv[1], 0.f);
        o0.z = fmaxf(acc[i][2] + bv[2], 0.f);
        o0.w = fmaxf(acc[i][3] + bv[3], 0.f);
        o1.x = fmaxf(acc[i][4] + bv[4], 0.f);
        o1.y = fmaxf(acc[i][5] + bv[5], 0.f);
        o1.z = fmaxf(acc[i][6] + bv[6], 0.f);
        o1.w = fmaxf(acc[i][7] + bv[7], 0.f);
        *(f4*)&sH[r][swz4(r, c0a)]      = o0;
        *(f4*)&sH[r][swz4(r, c0a + 64)] = o1;
    }
}
__global__ __launch_bounds__(256, 2)
void edge_kernel(const float* __restrict__ nf, const float* __restrict__ ef,
                 const int* __restrict__ snd, const int* __restrict__ rcv,
                 const float* __restrict__ W1, const float* __restrict__ b1,
                 const float* __restrict__ W2, const float* __restrict__ b2,
                 const float* __restrict__ W3, const float* __restrict__ b3,
                 const float* __restrict__ gam, const float* __restrict__ bet,
                 float* __restrict__ edge_out, float* __restrict__ agg) {
    __shared__ float sX[TM][64];
    __shared__ float sW[64][128];
    __shared__ float sH[TM][128];
    const int t   = threadIdx.x;
    const int r0  = (t >> 4) * 4;
    const int c0a = (t & 15) * 4;
    const int e0  = blockIdx.x * TM;
    const int ms = t >> 2;
    const int kq = (t & 3) * 4;
    float acc[4][8];
    zero_acc32(acc);
    for (int kc = 0; kc < 6; ++kc) {
        __syncthreads();
        stage_w32(W1 + (size_t)kc * 64 * 128, sW, t);
        {
            const int e = e0 + ms;
            const float* src;
            if (kc < 2)      src = nf + (size_t)snd[e] * D + kc * 64;
            else if (kc < 4) src = nf + (size_t)rcv[e] * D + (kc - 2) * 64;
            else             src = ef + (size_t)e * D + (kc - 4) * 64;
            const int g = (ms >> 2) & 3;
#pragma unroll
            for (int i = 0; i < 4; ++i) {
                const f4 x = *(const f4*)&src[(kq + i) * 4];
                *(f4*)&sX[ms][((kq + i) ^ g) << 2] = x;
            }
        }
        __syncthreads();
        kloop32<64>(&sX[0][0], 0, sW, r0, c0a, acc);
    }
    bias_relu32(b1, acc, sH, r0, c0a);
    zero_acc32(acc);
    for (int kc = 0; kc < 2; ++kc) {
        __syncthreads();
        stage_w32(W2 + (size_t)kc * 64 * 128, sW, t);
        __syncthreads();
        kloop32<128>(&sH[0][0], kc * 64, sW, r0, c0a, acc);
    }
    __syncthreads();
    bias_relu32(b2, acc, sH, r0, c0a);
    zero_acc32(acc);
    for (int kc = 0; kc < 2; ++kc) {
        __syncthreads();
        stage_w32(W3 + (size_t)kc * 64 * 128, sW, t);
        __syncthreads();
        kloop32<128>(&sH[0][0], kc * 64, sW, r0, c0a, acc);
    }
    {
        const f4 b30 = *(const f4*)&b3[c0a];
        const f4 b31 = *(const f4*)&b3[c0a + 64];
        const float bv[8] = {b30.x, b30.y, b30.z, b30.w, b31.x, b31.y, b31.z, b31.w};
        const f4 g0 = *(const f4*)&gam[c0a];
        const f4 g1 = *(const f4*)&gam[c0a + 64];
        const float gv[8] = {g0.x, g0.y, g0.z, g0.w, g1.x, g1.y, g1.z, g1.w};
        const f4 be0 = *(const f4*)&bet[c0a];
        const f4 be1 = *(const f4*)&bet[c0a + 64];
        const float ev[8] = {be0.x, be0.y, be0.z, be0.w, be1.x, be1.y, be1.z, be1.w};
#pragma unroll
        for (int i = 0; i < 4; ++i) {
            float h[8];
            float s = 0.f, ss = 0.f;
#pragma unroll
            for (int j = 0; j < 8; ++j) {
                h[j] = acc[i][j] + bv[j];
                s += h[j];
                ss = fmaf(h[j], h[j], ss);
            }
#pragma unroll
            for (int m = 1; m < 16; m <<= 1) {
                s  += __shfl_xor(s, m, 64);
                ss += __shfl_xor(ss, m, 64);
            }
            const float mu   = s * (1.f / 128.f);
            const float var  = ss * (1.f / 128.f) - mu * mu;
            const float rstd = rsqrtf(var + 1e-6f);
            const int e = e0 + r0 + i;
            float v[8];
#pragma unroll
            for (int j = 0; j < 8; ++j)
                v[j] = (h[j] - mu) * rstd * gv[j] + ev[j];
            if (agg) {
                const int dst = rcv[e];
#pragma unroll
                for (int j = 0; j < 8; ++j) {
                    const int col = c0a + ((j < 4) ? j : (60 + j));
                    atomicAdd(&agg[(size_t)dst * D + col], v[j]);
                }
            }
            const f4 er0 = *(const f4*)&ef[(size_t)e * D + c0a];
            const f4 er1 = *(const f4*)&ef[(size_t)e * D + c0a + 64];
            f4 o0, o1;
            o0.x = v[0] + er0.x; o0.y = v[1] + er0.y;
            o0.z = v[2] + er0.z; o0.w = v[3] + er0.w;
            o1.x = v[4] + er1.x; o1.y = v[5] + er1.y;
            o1.z = v[6] + er1.z; o1.w = v[7] + er1.w;
            *(f4*)&edge_out[(size_t)e * D + c0a]      = o0;
            *(f4*)&edge_out[(size_t)e * D + c0a + 64] = o1;
        }
    }
}
__global__ __launch_bounds__(256, 2)
void node_kernel(const float* __restrict__ nf, const float* __restrict__ agg,
                 const float* __restrict__ W1, const float* __restrict__ b1,
                 const float* __restrict__ W2, const float* __restrict__ b2,
                 const float* __restrict__ W3, const float* __restrict__ b3,
                 const float* __restrict__ gam, const float* __restrict__ bet,
                 float* __restrict__ node_out) {
    __shared__ float sX[TM][64];
    __shared__ float sW[64][128];
    __shared__ float sH[TM][128];
    const int t   = threadIdx.x;
    const int r0  = (t >> 4) * 4;
    const int c0a = (t & 15) * 4;
    const int n0  = blockIdx.x * TM;
    const int ms = t >> 2;
    const int kq = (t & 3) * 4;
    float acc[4][8];
    zero_acc32(acc);
    for (int kc = 0; kc < 4; ++kc) {
        __syncthreads();
        stage_w32(W1 + (size_t)kc * 64 * 128, sW, t);
        {
            int n = n0 + ms;
            if (n >= N_NODES) n = N_NODES - 1;
            const float* src = (kc < 2) ? nf  + (size_t)n * D + kc * 64
                                        : agg + (size_t)n * D + (kc - 2) * 64;
            const int g = (ms >> 2) & 3;
#pragma unroll
            for (int i = 0; i < 4; ++i) {
                const f4 x = *(const f4*)&src[(kq + i) * 4];
                *(f4*)&sX[ms][((kq + i) ^ g) << 2] = x;
            }
        }
        __syncthreads();
        kloop32<64>(&sX[0][0], 0, sW, r0, c0a, acc);
    }
    bias_relu32(b1, acc, sH, r0, c0a);
    zero_acc32(acc);
    for (int kc = 0; kc < 2; ++kc) {
        __syncthreads();
        stage_w32(W2 + (size_t)kc * 64 * 128, sW, t);
        __syncthreads();
        kloop32<128>(&sH[0][0], kc * 64, sW, r0, c0a, acc);
    }
    __syncthreads();
    bias_relu32(b2, acc, sH, r0, c0a);
    zero_acc32(acc);
    for (int kc = 0; kc < 2; ++kc) {
        __syncthreads();
        stage_w32(W3 + (size_t)kc * 64 * 128, sW, t);
        __syncthreads();
        kloop32<128>(&sH[0][0], kc * 64, sW, r0, c0a, acc);
    }
    {
        const f4 b30 = *(const f4*)&b3[c0a];
        const f4 b31 = *(const f4*)&b3[c0a + 64];
        const float bv[8] = {b30.x, b30.y, b30.z, b30.w, b31.x, b31.y, b31.z, b31.w};
        const f4 g0 = *(const f4*)&gam[c0a];
        const f4 g1 = *(const f4*)&gam[c0a + 64];
        const float gv[8] = {g0.x, g0.y, g0.z, g0.w, g1.x, g1.y, g1.z, g1.w};
        const f4 be0 = *(const f4*)&bet[c0a];
        const f4 be1 = *(const f4*)&bet[c0a + 64];
        const float ev[8] = {be0.x, be0.y, be0.z, be0.w, be1.x, be1.y, be1.z, be1.w};
#pragma unroll
        for (int i = 0; i < 4; ++i) {
            float h[8];
            float s = 0.f, ss = 0.f;
#pragma unroll
            for (int j = 0; j < 8; ++j) {
                h[j] = acc[i][j] + bv[j];
                s += h[j];
                ss = fmaf(h[j], h[j], ss);
            }
#pragma unroll
            for (int m = 1; m < 16; m <<= 1) {
                s  += __shfl_xor(s, m, 64);
                ss += __shfl_xor(ss, m, 64);
            }
            const float mu   = s * (1.f / 128.f);
            const float var  = ss * (1.f / 128.f) - mu * mu;
            const float rstd = rsqrtf(var + 1e-6f);
            const int n = n0 + r0 + i;
            if (n < N_NODES) {
                const f4 nr0 = *(const f4*)&nf[(size_t)n * D + c0a];
                const f4 nr1 = *(const f4*)&nf[(size_t)n * D + c0a + 64];
                f4 o0, o1;
                o0.x = (h[0] - mu) * rstd * gv[0] + ev[0] + nr0.x;
                o0.y = (h[1] - mu) * rstd * gv[1] + ev[1] + nr0.y;
                o0.z = (h[2] - mu) * rstd * gv[2] + ev[2] + nr0.z;
                o0.w = (h[3] - mu) * rstd * gv[3] + ev[3] + nr0.w;
                o1.x = (h[4] - mu) * rstd * gv[4] + ev[4] + nr1.x;
                o1.y = (h[5] - mu) * rstd * gv[5] + ev[5] + nr1.y;
                o1.z = (h[6] - mu) * rstd * gv[6] + ev[6] + nr1.z;
                o1.w = (h[7] - mu) * rstd * gv[7] + ev[7] + nr1.w;
                *(f4*)&node_out[(size_t)n * D + c0a]      = o0;
                *(f4*)&node_out[(size_t)n * D + c0a + 64] = o1;
            }
        }
    }
}

extern "C" void kernel_launch(void* const* d_in, const int* in_sizes, int n_in,
                              void* d_out, int out_size, void* d_ws, size_t ws_size,
                              hipStream_t stream) {
    const float* nf  = (const float*)d_in[0];
    const float* ef  = (const float*)d_in[1];
    const int*   snd = (const int*)d_in[2];
    const int*   rcv = (const int*)d_in[3];
    const float* We1 = (const float*)d_in[4];
    const float* be1 = (const float*)d_in[5];
    const float* We2 = (const float*)d_in[6];
    const float* be2 = (const float*)d_in[7];
    const float* We3 = (const float*)d_in[8];
    const float* be3 = (const float*)d_in[9];
    const float* ge  = (const float*)d_in[10];
    const float* Be  = (const float*)d_in[11];
    const float* Wn1 = (const float*)d_in[12];
    const float* bn1 = (const float*)d_in[13];
    const float* Wn2 = (const float*)d_in[14];
    const float* bn2 = (const float*)d_in[15];
    const float* Wn3 = (const float*)d_in[16];
    const float* bn3 = (const float*)d_in[17];
    const float* gn  = (const float*)d_in[18];
    const float* Bn  = (const float*)d_in[19];

    float* out      = (float*)d_out;
    float* node_out = out;                          // 50000*128
    float* edge_out = out + (size_t)N_NODES * D;    // 400000*128

    // d_ws layout: [wtsE 160 KB][wtsN 128 KB][deg][ptr][cursor][eidx]
    const size_t wts_bytes = (size_t)(81920 + 65536) * sizeof(_Float16);  // 294912
    const size_t csr_bytes = (size_t)(N_NODES * 2 + (N_NODES + 1) + N_EDGES) * 4;

    if (ws_size >= wts_bytes + csr_bytes) {
        _Float16* wtsE = (_Float16*)d_ws;                 // 10 tiles x 8192
        _Float16* wtsN = wtsE + 81920;                    //  8 tiles x 8192
        int* deg    = (int*)((char*)d_ws + wts_bytes);
        int* ptr    = deg + N_NODES;
        int* cursor = ptr + N_NODES + 1;
        int* eidx   = cursor + N_NODES;

        prep_w<<<18, 256, 0, stream>>>(We1, We2, We3, Wn1, Wn2, Wn3, wtsE, wtsN);
        hipMemsetAsync(deg, 0, (size_t)N_NODES * sizeof(int), stream);
        hist_kernel<<<(N_EDGES + 255) / 256, 256, 0, stream>>>(rcv, deg);
        scan_kernel<<<1, 256, 0, stream>>>(deg, ptr, cursor);
        scatter_kernel<<<(N_EDGES + 255) / 256, 256, 0, stream>>>(rcv, cursor, eidx);

        edge_mfma<<<N_EDGES / TM, 256, 0, stream>>>(
            nf, ef, snd, rcv, wtsE, be1, be2, be3, ge, Be, edge_out);

        node_mfma<<<(N_NODES + TM - 1) / TM, 256, 0, stream>>>(
            nf, edge_out, ef, ptr, eidx, wtsN, bn1, bn2, bn3, gn, Bn, node_out);
    } else {
        // fallback: verified fp32 path (agg staged in node_out region)
        float* agg = node_out;
        hipMemsetAsync(agg, 0, (size_t)N_NODES * D * sizeof(float), stream);
        edge_kernel<<<N_EDGES / TM, 256, 0, stream>>>(
            nf, ef, snd, rcv, We1, be1, We2, be2, We3, be3, ge, Be, edge_out, agg);
        node_kernel<<<(N_NODES + TM - 1) / TM, 256, 0, stream>>>(
            nf, agg, Wn1, bn1, Wn2, bn2, Wn3, bn3, gn, Bn, node_out);
    }
}